// Round 6
// baseline (116.498 us; speedup 1.0000x reference)
//
#include <hip/hip_runtime.h>

#define NH 6
#define HEAD_DIM 32
#define CCH 192
#define HH 56
#define WW 56
#define HWSZ (HH * WW)            // 3136
#define KPOS 9
#define SCALE 0.17677669529663687f  // 32^-0.5
#define XPAD 61                   // LDS x-stride: c-groups land on distinct banks
#define ROWSZ (HEAD_DIM * XPAD)   // 1952 floats per staged row-plane
#define NROWS 4                   // staged rows per block
#define PAIRS 14                  // same-parity output-row pairs per parity

// Block (512 thr) = (bh, pair): outputs y0 and y0+2 (same parity), staging
// rows {y0-2, y0, y0+2, y0+4} of k and v into LDS with zero padding baked in.
// Waves 0-3 compute output y0; waves 4-7 compute y0+2. Taps for output
// y0+2w are staged rows {w, w+1, w+2}. Block order pair-major/bh-inner:
// (bh,p) and (bh,p+1) are 48 ids apart -> same XCD -> 2 shared rows hit L2.
__global__ __launch_bounds__(512, 4) void dilate_attn_pair(
    const float* __restrict__ q,
    const float* __restrict__ k,
    const float* __restrict__ v,
    float* __restrict__ out)
{
    __shared__ float ks[NROWS * ROWSZ];   // 31,232 B
    __shared__ float vs[NROWS * ROWSZ];   // 31,232 B  (total 62,464 B)

    const int bh       = blockIdx.x % 48;
    const int pair_lin = blockIdx.x / 48;        // 0..27
    const int parity   = pair_lin / PAIRS;       // 0 even rows, 1 odd rows
    const int p        = pair_lin % PAIRS;       // 0..13
    const int y0       = 4 * p + parity;         // first output row
    const int t        = threadIdx.x;

    // ---- stage 4 k/v rows into LDS (zero-padded; OOB rows -> zeros) ----
    const size_t plane = (size_t)bh * HEAD_DIM * HWSZ;
#pragma unroll
    for (int i = 0; i < 14; i++) {               // 14*512 = 7168 = 4*32*56
        const int e   = t + 512 * i;
        const int r   = e / 1792;                // staged row 0..3
        const int rem = e - r * 1792;
        const int d   = rem / WW;
        const int x   = rem - d * WW;
        const int sy  = y0 - 2 + 2 * r;
        const bool okr = (sy >= 0) & (sy < HH);
        const size_t g = plane + (size_t)d * HWSZ + (okr ? sy : 0) * WW + x;
        const float kvv = okr ? k[g] : 0.0f;
        const float vvv = okr ? v[g] : 0.0f;
        const int a = r * ROWSZ + d * XPAD + x + 2;
        ks[a] = kvv;
        vs[a] = vvv;
    }
    // pad columns x' in {0,1,58,59}: 4 rows * 32 d * 4 cols = 512 elems
    {
        const int r  = t >> 7;                   // 0..3
        const int rs = t & 127;
        const int d  = rs >> 2;
        const int xc = rs & 3;
        const int xp = (xc < 2) ? xc : (56 + xc);   // 0,1,58,59
        ks[r * ROWSZ + d * XPAD + xp] = 0.0f;
        vs[r * ROWSZ + d * XPAD + xp] = 0.0f;
    }
    __syncthreads();

    // ---- compute: wave-group w2 -> output row y0 + 2*w2 ----
    const int w2 = t >> 8;                       // 0 or 1
    const int tt = t & 255;
    const int px = tt >> 2;                      // 0..63 (valid < 56)
    const int c  = tt & 3;                       // dim-octet: dims 8c..8c+7
    if (px >= WW) return;                        // no further barriers

    const int y = y0 + 2 * w2;

    // q for this (pixel, dim-octet)
    float qreg[8];
    {
        const float* qb = q + plane + (size_t)(8 * c) * HWSZ + y * WW + px;
#pragma unroll
        for (int j = 0; j < 8; j++) qreg[j] = qb[j * HWSZ];
    }

    // QK^T from LDS: output y taps staged rows w2, w2+1, w2+2; x' = px+2*ix
    float lg[KPOS];
#pragma unroll
    for (int rr = 0; rr < 3; rr++) {
        const float* kr = ks + (w2 + rr) * ROWSZ + (8 * c) * XPAD + px;
        float a0 = 0.f, a1 = 0.f, a2 = 0.f;
#pragma unroll
        for (int j = 0; j < 8; j++) {
            const float* pp = kr + j * XPAD;
            const float qj = qreg[j];
            a0 = fmaf(qj, pp[0], a0);
            a1 = fmaf(qj, pp[2], a1);
            a2 = fmaf(qj, pp[4], a2);
        }
        lg[3 * rr + 0] = a0;
        lg[3 * rr + 1] = a1;
        lg[3 * rr + 2] = a2;
    }

    // reduce partial dots over the 4 c-lanes (lanes 4px..4px+3)
#pragma unroll
    for (int kk = 0; kk < KPOS; kk++) {
        float s = lg[kk];
        s += __shfl_xor(s, 1);
        s += __shfl_xor(s, 2);
        lg[kk] = s * SCALE;
    }

    // softmax over 9 taps (redundant per lane)
    float m = lg[0];
#pragma unroll
    for (int kk = 1; kk < KPOS; kk++) m = fmaxf(m, lg[kk]);
    float ssum = 0.f;
    float w[KPOS];
#pragma unroll
    for (int kk = 0; kk < KPOS; kk++) {
        w[kk] = __expf(lg[kk] - m);
        ssum += w[kk];
    }
    const float inv = 1.f / ssum;
#pragma unroll
    for (int kk = 0; kk < KPOS; kk++) w[kk] *= inv;

    // PV from LDS
    float acc[8];
#pragma unroll
    for (int j = 0; j < 8; j++) acc[j] = 0.f;
#pragma unroll
    for (int rr = 0; rr < 3; rr++) {
        const float* vr = vs + (w2 + rr) * ROWSZ + (8 * c) * XPAD + px;
        const float w0 = w[3 * rr + 0];
        const float w1 = w[3 * rr + 1];
        const float w2f = w[3 * rr + 2];
#pragma unroll
        for (int j = 0; j < 8; j++) {
            const float* pp = vr + j * XPAD;
            float a = acc[j];
            a = fmaf(w0,  pp[0], a);
            a = fmaf(w1,  pp[2], a);
            a = fmaf(w2f, pp[4], a);
            acc[j] = a;
        }
    }

    // store: out[b, y, px, h*32 + 8c .. +7]
    const int h = bh % NH;
    const int b = bh / NH;
    float* ob = out + ((size_t)((b * HH + y) * WW + px)) * CCH
                    + h * HEAD_DIM + 8 * c;
    reinterpret_cast<float4*>(ob)[0] = make_float4(acc[0], acc[1], acc[2], acc[3]);
    reinterpret_cast<float4*>(ob)[1] = make_float4(acc[4], acc[5], acc[6], acc[7]);
}

extern "C" void kernel_launch(void* const* d_in, const int* in_sizes, int n_in,
                              void* d_out, int out_size, void* d_ws, size_t ws_size,
                              hipStream_t stream) {
    const float* q = (const float*)d_in[0];
    const float* k = (const float*)d_in[1];
    const float* v = (const float*)d_in[2];
    float* out = (float*)d_out;

    const int blocks = 48 * 2 * PAIRS;   // 1344
    dilate_attn_pair<<<blocks, 512, 0, stream>>>(q, k, v, out);
}